// Round 18
// baseline (266.860 us; speedup 1.0000x reference)
//
#include <hip/hip_runtime.h>
#include <hip/hip_bf16.h>
#include <stdint.h>
#include <stddef.h>

#define NVOX 262144
#define CCH 128
#define BN_EPS 1e-3f

typedef __attribute__((ext_vector_type(8))) short bfrag;   // 8 bf16 = 4 VGPRs
typedef __attribute__((ext_vector_type(4))) float f4;      // 4 f32

__device__ __forceinline__ unsigned short f2bf(float f) {
  union { float f; unsigned u; } v; v.f = f;
  unsigned r = v.u + 0x7fffu + ((v.u >> 16) & 1u);   // RNE (inputs finite)
  return (unsigned short)(r >> 16);
}

__device__ __forceinline__ bfrag pack8(f4 x, f4 y) {
  bfrag r;
  r[0] = (short)f2bf(x[0]); r[1] = (short)f2bf(x[1]);
  r[2] = (short)f2bf(x[2]); r[3] = (short)f2bf(x[3]);
  r[4] = (short)f2bf(y[0]); r[5] = (short)f2bf(y[1]);
  r[6] = (short)f2bf(y[2]); r[7] = (short)f2bf(y[3]);
  return r;
}

// minimal-op sigmoid via LLVM intrinsics: rcp(1 + 2^(-x*log2(e))).
__device__ __forceinline__ float sigmoidf_(float x) {
  const float e = __builtin_amdgcn_exp2f(x * -1.44269504f);
  return __builtin_amdgcn_rcpf(1.f + e);
}

__device__ __forceinline__ float bf2f(unsigned short h) {
  union { unsigned u; float f; } v; v.u = ((unsigned)h) << 16; return v.f;
}

// ---------------------------------------------------------------------------
// Pre-swizzle W1/W2/W3 into MFMA B-fragment order, bf16:
// region r = conv*3+tap (conv: 0=W1, 1=W2, 2=W3); frag = (r*4 + kc)*8 + tile
// lane holds B[k = kc*32 + (lane>>4)*8 + e][col = tile*16 + (lane&15)]
// ---------------------------------------------------------------------------
__global__ void prep_wfrag(const float* __restrict__ W1, const float* __restrict__ W2,
                           const float* __restrict__ W3, unsigned short* __restrict__ wf) {
  const int frag = blockIdx.x;           // 0..287
  const int tile = frag & 7;
  const int kc   = (frag >> 3) & 3;
  const int tap  = (frag >> 5) % 3;
  const int conv = frag / 96;
  const float* W = (conv == 0) ? W1 : ((conv == 1) ? W2 : W3);
  const int l   = threadIdx.x;           // 0..63
  const int col = tile * 16 + (l & 15);
  const int k0  = kc * 32 + (l >> 4) * 8;
  bfrag o;
#pragma unroll
  for (int e = 0; e < 8; ++e)
    o[e] = (short)f2bf(W[(size_t)(tap * CCH + k0 + e) * CCH + col]);
  *reinterpret_cast<bfrag*>(wf + (size_t)frag * 512 + l * 8) = o;
}

// ---------------------------------------------------------------------------
// BN scale/shift tables: bn[6][128] = {sc0, sh0, sc2, sh2, sc3, sh3}
// ---------------------------------------------------------------------------
__global__ void prep_bn(const float* g0, const float* b0, const float* m0, const float* v0,
                        const float* g2, const float* b2, const float* m2, const float* v2,
                        const float* g3, const float* b3, const float* m3, const float* v3,
                        float* __restrict__ bn) {
  const int c = threadIdx.x;
  const float s0 = g0[c] * rsqrtf(v0[c] + BN_EPS);
  const float s2 = g2[c] * rsqrtf(v2[c] + BN_EPS);
  const float s3 = g3[c] * rsqrtf(v3[c] + BN_EPS);
  bn[0 * CCH + c] = s0; bn[1 * CCH + c] = b0[c] - m0[c] * s0;
  bn[2 * CCH + c] = s2; bn[3 * CCH + c] = b2[c] - m2[c] * s2;
  bn[4 * CCH + c] = s3; bn[5 * CCH + c] = b3[c] - m3[c] * s3;
}

// ---------------------------------------------------------------------------
// Features fp32 -> bf16 (row N = zeros, the sentinel row)
// ---------------------------------------------------------------------------
__global__ void prep_bf16(const float* __restrict__ feats, unsigned short* __restrict__ fbf) {
  const size_t base = ((size_t)blockIdx.x * 256 + threadIdx.x) * 8;
  const f4 x = *reinterpret_cast<const f4*>(feats + base);
  const f4 y = *reinterpret_cast<const f4*>(feats + base + 4);
  *reinterpret_cast<bfrag*>(fbf + base) = pack8(x, y);
  if (blockIdx.x == 0 && threadIdx.x < 16) {
    bfrag z = {0, 0, 0, 0, 0, 0, 0, 0};
    *reinterpret_cast<bfrag*>(fbf + (size_t)NVOX * CCH + threadIdx.x * 8) = z;
  }
}

// ---------------------------------------------------------------------------
// v18 = v17 with the LDS B-path DELETED: wfrag is 288 KB and L2-resident, so
// B fragments are read directly from global (wave-uniform base + lane*16B) --
// B demand ~1.07 GB ~ 10 TB/s, well under the 34.5 TB/s L2 ceiling.
// Removes: all barriers, both fillconv serializations, the 48 KB LDS.
// Blocks shrink to 256 threads = 4 fully-independent waves (16 rows x 64 cols
// each, 64 rows/block); occupancy VGPR-limited: launch_bounds(256,6) -> cap 85
// -> 6 waves/SIMD, zero lockstep. Keeps: wave-uniform sparsity skip, preissued
// first-valid gather, fast sigmoid, folded activations, bf16 mirror+epilogue.
// ---------------------------------------------------------------------------
__global__ __launch_bounds__(256, 6)
void recon_v18(const unsigned short* __restrict__ fbf,
               const unsigned short* __restrict__ wfrag,
               const float* __restrict__ bn,
               const int* __restrict__ nbrz, const int* __restrict__ nbrx,
               const int* __restrict__ nbry,
               float* __restrict__ out) {
  const int tid  = threadIdx.x;
  const int lane = tid & 63;
  const int w    = tid >> 6;        // wave 0..3
  const int l15  = lane & 15;
  const int lhi  = lane >> 4;       // 0..3
  const int cb   = blockIdx.x & 1;  // 64-col half
  const int row0 = (blockIdx.x >> 1) * 64;
  const int wrow = row0 + w * 16;

  // ---- neighbor indices for this lane's row (4-lane dup across lhi) ----
  const int row = wrow + l15;
  const int rg  = row * 3;
  const int izp = nbrz[rg + 0], izn = nbrz[rg + 2];
  const int ixp = nbrx[rg + 0], ixn = nbrx[rg + 2];
  const int iyp = nbry[rg + 0], iyn = nbry[rg + 2];

  const bool azp = __any(izp != NVOX), azn = __any(izn != NVOX);
  const bool axp = __any(ixp != NVOX), axn = __any(ixn != NVOX);
  const bool ayp = __any(iyp != NVOX), ayn = __any(iyn != NVOX);

  bfrag aF[4];   // gathered-neighbor fragments
  bfrag aS[4];   // self-row fragments (reused by all 3 center taps)

#define LOADF(DST, IDX) {                                                     \
    const char* p = (const char*)fbf + ((size_t)(unsigned)(IDX) << 8) + (lhi << 4); \
    DST[0] = *reinterpret_cast<const bfrag*>(p);                              \
    DST[1] = *reinterpret_cast<const bfrag*>(p + 64);                         \
    DST[2] = *reinterpret_cast<const bfrag*>(p + 128);                        \
    DST[3] = *reinterpret_cast<const bfrag*>(p + 192);                        \
  }

  // B fragments straight from global (L2-hot). REGION in 0..8:
  // frag addr = wfrag + REGION*16384 + kc*4096 + cb*2048 + ct*512 + lane*8 (shorts)
#define TAP(REGION, AFR, ACCS) {                                              \
    const unsigned short* bs = wfrag + (size_t)(REGION) * 16384               \
                               + (cb << 11) + lane * 8;                       \
    _Pragma("unroll")                                                         \
    for (int kc = 0; kc < 4; ++kc) {                                          \
      _Pragma("unroll")                                                       \
      for (int ct = 0; ct < 4; ++ct) {                                        \
        const bfrag b = *reinterpret_cast<const bfrag*>(                      \
            bs + kc * 4096 + ct * 512);                                       \
        ACCS[ct] = __builtin_amdgcn_mfma_f32_16x16x32_bf16(                   \
            AFR[kc], b, ACCS[ct], 0, 0, 0);                                   \
      } } }

  // One conv (regions RP=prev, RS=self, RN=next): preload first valid
  // off-center A; the self tap's B-loads + MFMAs cover its latency.
#define CONV(VP, VN, IP, IN, RP, RS, RN, ACCS)                                \
  {                                                                           \
    if (VP)      LOADF(aF, IP)                                                \
    else if (VN) LOADF(aF, IN)                                                \
    TAP(RS, aS, ACCS)                                                         \
    if (VP) {                                                                 \
      TAP(RP, aF, ACCS)                                                       \
      if (VN) { LOADF(aF, IN)  TAP(RN, aF, ACCS) }                            \
    } else if (VN) {                                                          \
      TAP(RN, aF, ACCS)                                                       \
    }                                                                         \
  }

  LOADF(aS, row)   // self row (sentinel-free), reused by the 3 center taps

  f4 acc[4], run[4];
#pragma unroll
  for (int ct = 0; ct < 4; ++ct) {
    acc[ct] = f4{0.f, 0.f, 0.f, 0.f};
    run[ct] = f4{0.f, 0.f, 0.f, 0.f};
  }

  // ================= conv-z (W1): regions 0,1,2 =================
  CONV(azp, azn, izp, izn, 0, 1, 2, acc)
  // fold: run = sigmoid(bn2(sigmoid(bn0(acc)))); acc = 0
#pragma unroll
  for (int ct = 0; ct < 4; ++ct) {
    const int col = cb * 64 + ct * 16 + l15;
    const float sc0 = bn[0 * CCH + col], sh0 = bn[1 * CCH + col];
    const float sc2 = bn[2 * CCH + col], sh2 = bn[3 * CCH + col];
#pragma unroll
    for (int j = 0; j < 4; ++j) {
      const float u = sigmoidf_(sc0 * acc[ct][j] + sh0);
      run[ct][j] = sigmoidf_(sc2 * u + sh2);
    }
    acc[ct] = f4{0.f, 0.f, 0.f, 0.f};
  }
  // ================= conv-x (W3): regions 6,7,8 =================
  CONV(axp, axn, ixp, ixn, 6, 7, 8, acc)
  // fold: run += sigmoid(bn3(acc))
#pragma unroll
  for (int ct = 0; ct < 4; ++ct) {
    const int col = cb * 64 + ct * 16 + l15;
    const float sc3 = bn[4 * CCH + col], sh3 = bn[5 * CCH + col];
#pragma unroll
    for (int j = 0; j < 4; ++j)
      run[ct][j] += sigmoidf_(sc3 * acc[ct][j] + sh3);
  }
  // ================= conv-y (W2): regions 3,4,5, raw into run =================
  CONV(ayp, ayn, iyp, iyn, 3, 4, 5, run)

#undef CONV
#undef TAP
#undef LOADF

  // ---- epilogue: multiply by features (bf16, cache-hot), store fp32 ----
#pragma unroll
  for (int ct = 0; ct < 4; ++ct) {
    const int col = cb * 64 + ct * 16 + l15;
#pragma unroll
    for (int j = 0; j < 4; ++j) {
      const int r = wrow + (lhi << 2) + j;
      const size_t o = ((size_t)r << 7) + col;
      out[o] = run[ct][j] * bf2f(fbf[o]);
    }
  }
}

// ---------------------------------------------------------------------------
// Last-resort fallback: exact fp32
// ---------------------------------------------------------------------------
__global__ void recon_naive(const float* __restrict__ feats,
    const float* __restrict__ W1, const float* __restrict__ W2, const float* __restrict__ W3,
    const int* __restrict__ nbrz, const int* __restrict__ nbry, const int* __restrict__ nbrx,
    const float* g0, const float* b0, const float* m0, const float* v0,
    const float* g2, const float* b2, const float* m2, const float* v2,
    const float* g3, const float* b3, const float* m3, const float* v3,
    float* __restrict__ out) {
  __shared__ float rows[3][CCH];
  const int n = blockIdx.x;
  const int d = threadIdx.x;
  float res[3];
#pragma unroll
  for (int conv = 0; conv < 3; ++conv) {
    const int* nbr  = (conv == 0) ? nbrz : ((conv == 1) ? nbry : nbrx);
    const float* W  = (conv == 0) ? W1 : ((conv == 1) ? W2 : W3);
#pragma unroll
    for (int tap = 0; tap < 3; ++tap) {
      const int idx = nbr[n * 3 + tap];
      rows[tap][d] = ((unsigned)idx < (unsigned)NVOX) ? feats[((size_t)idx << 7) + d] : 0.f;
    }
    __syncthreads();
    const float* rflat = &rows[0][0];
    float s = 0.f;
    for (int k = 0; k < 3 * CCH; ++k) s += rflat[k] * W[(size_t)k * CCH + d];
    res[conv] = s;
    __syncthreads();
  }
  const float sc0 = g0[d] * rsqrtf(v0[d] + BN_EPS), sh0 = b0[d] - m0[d] * sc0;
  const float sc2 = g2[d] * rsqrtf(v2[d] + BN_EPS), sh2 = b2[d] - m2[d] * sc2;
  const float sc3 = g3[d] * rsqrtf(v3[d] + BN_EPS), sh3 = b3[d] - m3[d] * sc3;
  float u = 1.f / (1.f + __expf(-(sc0 * res[0] + sh0)));
  u = 1.f / (1.f + __expf(-(sc2 * u + sh2)));
  const float s3v = 1.f / (1.f + __expf(-(sc3 * res[2] + sh3)));
  out[((size_t)n << 7) + d] = (u + res[1] + s3v) * feats[((size_t)n << 7) + d];
}

extern "C" void kernel_launch(void* const* d_in, const int* in_sizes, int n_in,
                              void* d_out, int out_size, void* d_ws, size_t ws_size,
                              hipStream_t stream) {
  const float* feats = (const float*)d_in[0];
  const float* W1 = (const float*)d_in[1];
  const float* W2 = (const float*)d_in[2];
  const float* W3 = (const float*)d_in[3];
  const float* g0 = (const float*)d_in[4];
  const float* b0 = (const float*)d_in[5];
  const float* m0 = (const float*)d_in[6];
  const float* v0 = (const float*)d_in[7];
  const float* g2 = (const float*)d_in[8];
  const float* b2 = (const float*)d_in[9];
  const float* m2 = (const float*)d_in[10];
  const float* v2 = (const float*)d_in[11];
  const float* g3 = (const float*)d_in[12];
  const float* b3 = (const float*)d_in[13];
  const float* m3 = (const float*)d_in[14];
  const float* v3 = (const float*)d_in[15];
  const int* nz = (const int*)d_in[16];
  const int* ny = (const int*)d_in[17];
  const int* nx = (const int*)d_in[18];
  float* out = (float*)d_out;

  const size_t wf_bytes = 288u * 1024u;                              // 294912
  const size_t bn_bytes = 4096u;                                     // 6*128*4 padded
  const size_t fb_bytes = ((size_t)NVOX + 1) * CCH * sizeof(short);  // 67.1 MB
  if (ws_size >= wf_bytes + bn_bytes + fb_bytes) {
    unsigned short* wf  = (unsigned short*)d_ws;
    float*          bnt = (float*)((char*)d_ws + wf_bytes);
    unsigned short* fbf = (unsigned short*)((char*)d_ws + wf_bytes + bn_bytes);
    hipLaunchKernelGGL(prep_wfrag, dim3(288), dim3(64), 0, stream, W1, W2, W3, wf);
    hipLaunchKernelGGL(prep_bn, dim3(1), dim3(CCH), 0, stream,
                       g0, b0, m0, v0, g2, b2, m2, v2, g3, b3, m3, v3, bnt);
    hipLaunchKernelGGL(prep_bf16, dim3((NVOX * CCH) / (256 * 8)), dim3(256), 0, stream,
                       feats, fbf);
    hipLaunchKernelGGL(recon_v18, dim3((NVOX / 64) * 2), dim3(256), 0, stream,
                       fbf, wf, bnt, nz, nx, ny, out);
  } else {
    hipLaunchKernelGGL(recon_naive, dim3(NVOX), dim3(CCH), 0, stream,
                       feats, W1, W2, W3, nz, ny, nx,
                       g0, b0, m0, v0, g2, b2, m2, v2, g3, b3, m3, v3, out);
  }
}

// Round 19
// 161.540 us; speedup vs baseline: 1.6520x; 1.6520x over previous
//
#include <hip/hip_runtime.h>
#include <hip/hip_bf16.h>
#include <stdint.h>
#include <stddef.h>

#define NVOX 262144
#define CCH 128
#define BN_EPS 1e-3f

typedef __attribute__((ext_vector_type(8))) short bfrag;   // 8 bf16 = 4 VGPRs
typedef __attribute__((ext_vector_type(4))) float f4;      // 4 f32

__device__ __forceinline__ unsigned short f2bf(float f) {
  union { float f; unsigned u; } v; v.f = f;
  unsigned r = v.u + 0x7fffu + ((v.u >> 16) & 1u);   // RNE (inputs finite)
  return (unsigned short)(r >> 16);
}

__device__ __forceinline__ bfrag pack8(f4 x, f4 y) {
  bfrag r;
  r[0] = (short)f2bf(x[0]); r[1] = (short)f2bf(x[1]);
  r[2] = (short)f2bf(x[2]); r[3] = (short)f2bf(x[3]);
  r[4] = (short)f2bf(y[0]); r[5] = (short)f2bf(y[1]);
  r[6] = (short)f2bf(y[2]); r[7] = (short)f2bf(y[3]);
  return r;
}

// minimal-op sigmoid via LLVM intrinsics: rcp(1 + 2^(-x*log2(e))).
__device__ __forceinline__ float sigmoidf_(float x) {
  const float e = __builtin_amdgcn_exp2f(x * -1.44269504f);
  return __builtin_amdgcn_rcpf(1.f + e);
}

__device__ __forceinline__ float bf2f(unsigned short h) {
  union { unsigned u; float f; } v; v.u = ((unsigned)h) << 16; return v.f;
}

// ---------------------------------------------------------------------------
// Pre-swizzle W1/W2/W3 into MFMA B-fragment order, bf16:
// region r = conv*3+tap (conv: 0=W1, 1=W2, 2=W3); frag = (r*4 + kc)*8 + tile
// lane holds B[k = kc*32 + (lane>>4)*8 + e][col = tile*16 + (lane&15)]
// ---------------------------------------------------------------------------
__global__ void prep_wfrag(const float* __restrict__ W1, const float* __restrict__ W2,
                           const float* __restrict__ W3, unsigned short* __restrict__ wf) {
  const int frag = blockIdx.x;           // 0..287
  const int tile = frag & 7;
  const int kc   = (frag >> 3) & 3;
  const int tap  = (frag >> 5) % 3;
  const int conv = frag / 96;
  const float* W = (conv == 0) ? W1 : ((conv == 1) ? W2 : W3);
  const int l   = threadIdx.x;           // 0..63
  const int col = tile * 16 + (l & 15);
  const int k0  = kc * 32 + (l >> 4) * 8;
  bfrag o;
#pragma unroll
  for (int e = 0; e < 8; ++e)
    o[e] = (short)f2bf(W[(size_t)(tap * CCH + k0 + e) * CCH + col]);
  *reinterpret_cast<bfrag*>(wf + (size_t)frag * 512 + l * 8) = o;
}

// ---------------------------------------------------------------------------
// BN scale/shift tables: bn[6][128] = {sc0, sh0, sc2, sh2, sc3, sh3}
// ---------------------------------------------------------------------------
__global__ void prep_bn(const float* g0, const float* b0, const float* m0, const float* v0,
                        const float* g2, const float* b2, const float* m2, const float* v2,
                        const float* g3, const float* b3, const float* m3, const float* v3,
                        float* __restrict__ bn) {
  const int c = threadIdx.x;
  const float s0 = g0[c] * rsqrtf(v0[c] + BN_EPS);
  const float s2 = g2[c] * rsqrtf(v2[c] + BN_EPS);
  const float s3 = g3[c] * rsqrtf(v3[c] + BN_EPS);
  bn[0 * CCH + c] = s0; bn[1 * CCH + c] = b0[c] - m0[c] * s0;
  bn[2 * CCH + c] = s2; bn[3 * CCH + c] = b2[c] - m2[c] * s2;
  bn[4 * CCH + c] = s3; bn[5 * CCH + c] = b3[c] - m3[c] * s3;
}

// ---------------------------------------------------------------------------
// Features fp32 -> bf16 (row N = zeros, the sentinel row)
// ---------------------------------------------------------------------------
__global__ void prep_bf16(const float* __restrict__ feats, unsigned short* __restrict__ fbf) {
  const size_t base = ((size_t)blockIdx.x * 256 + threadIdx.x) * 8;
  const f4 x = *reinterpret_cast<const f4*>(feats + base);
  const f4 y = *reinterpret_cast<const f4*>(feats + base + 4);
  *reinterpret_cast<bfrag*>(fbf + base) = pack8(x, y);
  if (blockIdx.x == 0 && threadIdx.x < 16) {
    bfrag z = {0, 0, 0, 0, 0, 0, 0, 0};
    *reinterpret_cast<bfrag*>(fbf + (size_t)NVOX * CCH + threadIdx.x * 8) = z;
  }
}

// ---------------------------------------------------------------------------
// v19 = v18 (barrier-free, LDS-free, B read directly from L2-resident wfrag)
// with the register squeeze removed: __launch_bounds__(256, 4) -> cap ~128
// (confirmed pattern: (512,4)->64; v18's (256,6) squeezed to 40 and spilled
// 314 MB of scratch). Residency now purely VGPR-limited: at ~64-80 regs the
// CU holds 6-8 waves/SIMD of fully-independent 16-row waves -- max TLP with
// zero lockstep. Keeps: wave-uniform sparsity skip, preissued first-valid
// gather, fast sigmoid, folded activations, bf16 mirror + epilogue.
// ---------------------------------------------------------------------------
__global__ __launch_bounds__(256, 4)
void recon_v19(const unsigned short* __restrict__ fbf,
               const unsigned short* __restrict__ wfrag,
               const float* __restrict__ bn,
               const int* __restrict__ nbrz, const int* __restrict__ nbrx,
               const int* __restrict__ nbry,
               float* __restrict__ out) {
  const int tid  = threadIdx.x;
  const int lane = tid & 63;
  const int w    = tid >> 6;        // wave 0..3
  const int l15  = lane & 15;
  const int lhi  = lane >> 4;       // 0..3
  const int cb   = blockIdx.x & 1;  // 64-col half
  const int row0 = (blockIdx.x >> 1) * 64;
  const int wrow = row0 + w * 16;

  // ---- neighbor indices for this lane's row (4-lane dup across lhi) ----
  const int row = wrow + l15;
  const int rg  = row * 3;
  const int izp = nbrz[rg + 0], izn = nbrz[rg + 2];
  const int ixp = nbrx[rg + 0], ixn = nbrx[rg + 2];
  const int iyp = nbry[rg + 0], iyn = nbry[rg + 2];

  const bool azp = __any(izp != NVOX), azn = __any(izn != NVOX);
  const bool axp = __any(ixp != NVOX), axn = __any(ixn != NVOX);
  const bool ayp = __any(iyp != NVOX), ayn = __any(iyn != NVOX);

  bfrag aF[4];   // gathered-neighbor fragments
  bfrag aS[4];   // self-row fragments (reused by all 3 center taps)

#define LOADF(DST, IDX) {                                                     \
    const char* p = (const char*)fbf + ((size_t)(unsigned)(IDX) << 8) + (lhi << 4); \
    DST[0] = *reinterpret_cast<const bfrag*>(p);                              \
    DST[1] = *reinterpret_cast<const bfrag*>(p + 64);                         \
    DST[2] = *reinterpret_cast<const bfrag*>(p + 128);                        \
    DST[3] = *reinterpret_cast<const bfrag*>(p + 192);                        \
  }

  // B fragments straight from global (L2-hot). REGION in 0..8:
  // frag addr = wfrag + REGION*16384 + kc*4096 + cb*2048 + ct*512 + lane*8 (shorts)
#define TAP(REGION, AFR, ACCS) {                                              \
    const unsigned short* bs = wfrag + (size_t)(REGION) * 16384               \
                               + (cb << 11) + lane * 8;                       \
    _Pragma("unroll")                                                         \
    for (int kc = 0; kc < 4; ++kc) {                                          \
      _Pragma("unroll")                                                       \
      for (int ct = 0; ct < 4; ++ct) {                                        \
        const bfrag b = *reinterpret_cast<const bfrag*>(                      \
            bs + kc * 4096 + ct * 512);                                       \
        ACCS[ct] = __builtin_amdgcn_mfma_f32_16x16x32_bf16(                   \
            AFR[kc], b, ACCS[ct], 0, 0, 0);                                   \
      } } }

  // One conv (regions RP=prev, RS=self, RN=next): preload first valid
  // off-center A; the self tap's B-loads + MFMAs cover its latency.
#define CONV(VP, VN, IP, IN, RP, RS, RN, ACCS)                                \
  {                                                                           \
    if (VP)      LOADF(aF, IP)                                                \
    else if (VN) LOADF(aF, IN)                                                \
    TAP(RS, aS, ACCS)                                                         \
    if (VP) {                                                                 \
      TAP(RP, aF, ACCS)                                                       \
      if (VN) { LOADF(aF, IN)  TAP(RN, aF, ACCS) }                            \
    } else if (VN) {                                                          \
      TAP(RN, aF, ACCS)                                                       \
    }                                                                         \
  }

  LOADF(aS, row)   // self row (sentinel-free), reused by the 3 center taps

  f4 acc[4], run[4];
#pragma unroll
  for (int ct = 0; ct < 4; ++ct) {
    acc[ct] = f4{0.f, 0.f, 0.f, 0.f};
    run[ct] = f4{0.f, 0.f, 0.f, 0.f};
  }

  // ================= conv-z (W1): regions 0,1,2 =================
  CONV(azp, azn, izp, izn, 0, 1, 2, acc)
  // fold: run = sigmoid(bn2(sigmoid(bn0(acc)))); acc = 0
#pragma unroll
  for (int ct = 0; ct < 4; ++ct) {
    const int col = cb * 64 + ct * 16 + l15;
    const float sc0 = bn[0 * CCH + col], sh0 = bn[1 * CCH + col];
    const float sc2 = bn[2 * CCH + col], sh2 = bn[3 * CCH + col];
#pragma unroll
    for (int j = 0; j < 4; ++j) {
      const float u = sigmoidf_(sc0 * acc[ct][j] + sh0);
      run[ct][j] = sigmoidf_(sc2 * u + sh2);
    }
    acc[ct] = f4{0.f, 0.f, 0.f, 0.f};
  }
  // ================= conv-x (W3): regions 6,7,8 =================
  CONV(axp, axn, ixp, ixn, 6, 7, 8, acc)
  // fold: run += sigmoid(bn3(acc))
#pragma unroll
  for (int ct = 0; ct < 4; ++ct) {
    const int col = cb * 64 + ct * 16 + l15;
    const float sc3 = bn[4 * CCH + col], sh3 = bn[5 * CCH + col];
#pragma unroll
    for (int j = 0; j < 4; ++j)
      run[ct][j] += sigmoidf_(sc3 * acc[ct][j] + sh3);
  }
  // ================= conv-y (W2): regions 3,4,5, raw into run =================
  CONV(ayp, ayn, iyp, iyn, 3, 4, 5, run)

#undef CONV
#undef TAP
#undef LOADF

  // ---- epilogue: multiply by features (bf16, cache-hot), store fp32 ----
#pragma unroll
  for (int ct = 0; ct < 4; ++ct) {
    const int col = cb * 64 + ct * 16 + l15;
#pragma unroll
    for (int j = 0; j < 4; ++j) {
      const int r = wrow + (lhi << 2) + j;
      const size_t o = ((size_t)r << 7) + col;
      out[o] = run[ct][j] * bf2f(fbf[o]);
    }
  }
}

// ---------------------------------------------------------------------------
// Last-resort fallback: exact fp32
// ---------------------------------------------------------------------------
__global__ void recon_naive(const float* __restrict__ feats,
    const float* __restrict__ W1, const float* __restrict__ W2, const float* __restrict__ W3,
    const int* __restrict__ nbrz, const int* __restrict__ nbry, const int* __restrict__ nbrx,
    const float* g0, const float* b0, const float* m0, const float* v0,
    const float* g2, const float* b2, const float* m2, const float* v2,
    const float* g3, const float* b3, const float* m3, const float* v3,
    float* __restrict__ out) {
  __shared__ float rows[3][CCH];
  const int n = blockIdx.x;
  const int d = threadIdx.x;
  float res[3];
#pragma unroll
  for (int conv = 0; conv < 3; ++conv) {
    const int* nbr  = (conv == 0) ? nbrz : ((conv == 1) ? nbry : nbrx);
    const float* W  = (conv == 0) ? W1 : ((conv == 1) ? W2 : W3);
#pragma unroll
    for (int tap = 0; tap < 3; ++tap) {
      const int idx = nbr[n * 3 + tap];
      rows[tap][d] = ((unsigned)idx < (unsigned)NVOX) ? feats[((size_t)idx << 7) + d] : 0.f;
    }
    __syncthreads();
    const float* rflat = &rows[0][0];
    float s = 0.f;
    for (int k = 0; k < 3 * CCH; ++k) s += rflat[k] * W[(size_t)k * CCH + d];
    res[conv] = s;
    __syncthreads();
  }
  const float sc0 = g0[d] * rsqrtf(v0[d] + BN_EPS), sh0 = b0[d] - m0[d] * sc0;
  const float sc2 = g2[d] * rsqrtf(v2[d] + BN_EPS), sh2 = b2[d] - m2[d] * sc2;
  const float sc3 = g3[d] * rsqrtf(v3[d] + BN_EPS), sh3 = b3[d] - m3[d] * sc3;
  float u = 1.f / (1.f + __expf(-(sc0 * res[0] + sh0)));
  u = 1.f / (1.f + __expf(-(sc2 * u + sh2)));
  const float s3v = 1.f / (1.f + __expf(-(sc3 * res[2] + sh3)));
  out[((size_t)n << 7) + d] = (u + res[1] + s3v) * feats[((size_t)n << 7) + d];
}

extern "C" void kernel_launch(void* const* d_in, const int* in_sizes, int n_in,
                              void* d_out, int out_size, void* d_ws, size_t ws_size,
                              hipStream_t stream) {
  const float* feats = (const float*)d_in[0];
  const float* W1 = (const float*)d_in[1];
  const float* W2 = (const float*)d_in[2];
  const float* W3 = (const float*)d_in[3];
  const float* g0 = (const float*)d_in[4];
  const float* b0 = (const float*)d_in[5];
  const float* m0 = (const float*)d_in[6];
  const float* v0 = (const float*)d_in[7];
  const float* g2 = (const float*)d_in[8];
  const float* b2 = (const float*)d_in[9];
  const float* m2 = (const float*)d_in[10];
  const float* v2 = (const float*)d_in[11];
  const float* g3 = (const float*)d_in[12];
  const float* b3 = (const float*)d_in[13];
  const float* m3 = (const float*)d_in[14];
  const float* v3 = (const float*)d_in[15];
  const int* nz = (const int*)d_in[16];
  const int* ny = (const int*)d_in[17];
  const int* nx = (const int*)d_in[18];
  float* out = (float*)d_out;

  const size_t wf_bytes = 288u * 1024u;                              // 294912
  const size_t bn_bytes = 4096u;                                     // 6*128*4 padded
  const size_t fb_bytes = ((size_t)NVOX + 1) * CCH * sizeof(short);  // 67.1 MB
  if (ws_size >= wf_bytes + bn_bytes + fb_bytes) {
    unsigned short* wf  = (unsigned short*)d_ws;
    float*          bnt = (float*)((char*)d_ws + wf_bytes);
    unsigned short* fbf = (unsigned short*)((char*)d_ws + wf_bytes + bn_bytes);
    hipLaunchKernelGGL(prep_wfrag, dim3(288), dim3(64), 0, stream, W1, W2, W3, wf);
    hipLaunchKernelGGL(prep_bn, dim3(1), dim3(CCH), 0, stream,
                       g0, b0, m0, v0, g2, b2, m2, v2, g3, b3, m3, v3, bnt);
    hipLaunchKernelGGL(prep_bf16, dim3((NVOX * CCH) / (256 * 8)), dim3(256), 0, stream,
                       feats, fbf);
    hipLaunchKernelGGL(recon_v19, dim3((NVOX / 64) * 2), dim3(256), 0, stream,
                       fbf, wf, bnt, nz, nx, ny, out);
  } else {
    hipLaunchKernelGGL(recon_naive, dim3(NVOX), dim3(CCH), 0, stream,
                       feats, W1, W2, W3, nz, ny, nx,
                       g0, b0, m0, v0, g2, b2, m2, v2, g3, b3, m3, v3, out);
  }
}

// Round 20
// 139.200 us; speedup vs baseline: 1.9171x; 1.1605x over previous
//
#include <hip/hip_runtime.h>
#include <hip/hip_bf16.h>
#include <stdint.h>
#include <stddef.h>

#define NVOX 262144
#define CCH 128
#define BN_EPS 1e-3f

typedef __attribute__((ext_vector_type(8))) short bfrag;   // 8 bf16 = 4 VGPRs
typedef __attribute__((ext_vector_type(4))) float f4;      // 4 f32

#define AS1 __attribute__((address_space(1)))
#define AS3 __attribute__((address_space(3)))

__device__ __forceinline__ unsigned short f2bf(float f) {
  union { float f; unsigned u; } v; v.f = f;
  unsigned r = v.u + 0x7fffu + ((v.u >> 16) & 1u);   // RNE (inputs finite)
  return (unsigned short)(r >> 16);
}

__device__ __forceinline__ bfrag pack8(f4 x, f4 y) {
  bfrag r;
  r[0] = (short)f2bf(x[0]); r[1] = (short)f2bf(x[1]);
  r[2] = (short)f2bf(x[2]); r[3] = (short)f2bf(x[3]);
  r[4] = (short)f2bf(y[0]); r[5] = (short)f2bf(y[1]);
  r[6] = (short)f2bf(y[2]); r[7] = (short)f2bf(y[3]);
  return r;
}

// minimal-op sigmoid via LLVM intrinsics: rcp(1 + 2^(-x*log2(e))).
__device__ __forceinline__ float sigmoidf_(float x) {
  const float e = __builtin_amdgcn_exp2f(x * -1.44269504f);
  return __builtin_amdgcn_rcpf(1.f + e);
}

__device__ __forceinline__ float bf2f(unsigned short h) {
  union { unsigned u; float f; } v; v.u = ((unsigned)h) << 16; return v.f;
}

// ---------------------------------------------------------------------------
// Pre-swizzle W1/W2/W3 into MFMA B-fragment order, bf16:
// region r = conv*3+tap (conv: 0=W1, 1=W2, 2=W3); frag = (r*4 + kc)*8 + tile
// lane holds B[k = kc*32 + (lane>>4)*8 + e][col = tile*16 + (lane&15)]
// ---------------------------------------------------------------------------
__global__ void prep_wfrag(const float* __restrict__ W1, const float* __restrict__ W2,
                           const float* __restrict__ W3, unsigned short* __restrict__ wf) {
  const int frag = blockIdx.x;           // 0..287
  const int tile = frag & 7;
  const int kc   = (frag >> 3) & 3;
  const int tap  = (frag >> 5) % 3;
  const int conv = frag / 96;
  const float* W = (conv == 0) ? W1 : ((conv == 1) ? W2 : W3);
  const int l   = threadIdx.x;           // 0..63
  const int col = tile * 16 + (l & 15);
  const int k0  = kc * 32 + (l >> 4) * 8;
  bfrag o;
#pragma unroll
  for (int e = 0; e < 8; ++e)
    o[e] = (short)f2bf(W[(size_t)(tap * CCH + k0 + e) * CCH + col]);
  *reinterpret_cast<bfrag*>(wf + (size_t)frag * 512 + l * 8) = o;
}

// ---------------------------------------------------------------------------
// BN scale/shift tables: bn[6][128] = {sc0, sh0, sc2, sh2, sc3, sh3}
// ---------------------------------------------------------------------------
__global__ void prep_bn(const float* g0, const float* b0, const float* m0, const float* v0,
                        const float* g2, const float* b2, const float* m2, const float* v2,
                        const float* g3, const float* b3, const float* m3, const float* v3,
                        float* __restrict__ bn) {
  const int c = threadIdx.x;
  const float s0 = g0[c] * rsqrtf(v0[c] + BN_EPS);
  const float s2 = g2[c] * rsqrtf(v2[c] + BN_EPS);
  const float s3 = g3[c] * rsqrtf(v3[c] + BN_EPS);
  bn[0 * CCH + c] = s0; bn[1 * CCH + c] = b0[c] - m0[c] * s0;
  bn[2 * CCH + c] = s2; bn[3 * CCH + c] = b2[c] - m2[c] * s2;
  bn[4 * CCH + c] = s3; bn[5 * CCH + c] = b3[c] - m3[c] * s3;
}

// ---------------------------------------------------------------------------
// Features fp32 -> bf16 (row N = zeros, the sentinel row)
// ---------------------------------------------------------------------------
__global__ void prep_bf16(const float* __restrict__ feats, unsigned short* __restrict__ fbf) {
  const size_t base = ((size_t)blockIdx.x * 256 + threadIdx.x) * 8;
  const f4 x = *reinterpret_cast<const f4*>(feats + base);
  const f4 y = *reinterpret_cast<const f4*>(feats + base + 4);
  *reinterpret_cast<bfrag*>(fbf + base) = pack8(x, y);
  if (blockIdx.x == 0 && threadIdx.x < 16) {
    bfrag z = {0, 0, 0, 0, 0, 0, 0, 0};
    *reinterpret_cast<bfrag*>(fbf + (size_t)NVOX * CCH + threadIdx.x * 8) = z;
  }
}

// ---------------------------------------------------------------------------
// v20 = v17 (best: 110 us main) + cross-conv gather preissue:
// each conv's first-valid off-center gather is issued EARLY -- conv-z's under
// the initial B-fill wait, conv-x's / conv-y's right after the previous
// fillconv (covered by the fold VALU + the barrier's vmcnt drain) -- instead
// of after the barrier. No new buffers (aF was dead at those points); live
// range grows ~16 regs -> launch_bounds(512,3), cap 85.
// Everything else identical to v17 (geometry, LDS plan, skip logic, fast
// sigmoid, folded activations, bf16 mirror + epilogue).
// ---------------------------------------------------------------------------
__global__ __launch_bounds__(512, 3)
void recon_v20(const unsigned short* __restrict__ fbf,
               const unsigned short* __restrict__ wfrag,
               const float* __restrict__ bn,
               const int* __restrict__ nbrz, const int* __restrict__ nbrx,
               const int* __restrict__ nbry,
               float* __restrict__ out) {
  __shared__ unsigned short Bb[24576];   // 48 KB: 3 slots x 16 frags x 1 KB

  const int tid  = threadIdx.x;
  const int lane = tid & 63;
  const int w    = tid >> 6;        // wave 0..7
  const int l15  = lane & 15;
  const int lhi  = lane >> 4;       // 0..3
  const int cb   = blockIdx.x & 1;  // 64-col half
  const int row0 = (blockIdx.x >> 1) * 128;   // 128 rows/block (v11/v17 geometry)
  const int wrow = row0 + w * 16;

  // Fill the 3 resident slots for one conv (region base RB: W1=0, W2=3, W3=6).
  auto fillconv = [&](int RB) {
#pragma unroll
    for (int i = 0; i < 6; ++i) {
      const int L    = w * 6 + i;        // local frag 0..47
      const int slot = L >> 4;           // tap 0..2
      const int sub  = L & 15;           // kc*4+ct
      const int g    = ((RB + slot) * 4 + (sub >> 2)) * 8 + cb * 4 + (sub & 3);
      __builtin_amdgcn_global_load_lds(
          (const AS1 void*)(wfrag + (size_t)g * 512 + lane * 8),
          (AS3 void*)((char*)Bb + L * 1024), 16, 0, 0);
    }
  };

  // ---- prologue: conv-z fill + neighbor indices ----
  fillconv(0);
  const int row = wrow + l15;
  const int rg  = row * 3;
  const int izp = nbrz[rg + 0], izn = nbrz[rg + 2];
  const int ixp = nbrx[rg + 0], ixn = nbrx[rg + 2];
  const int iyp = nbry[rg + 0], iyn = nbry[rg + 2];

  const bool azp = __any(izp != NVOX), azn = __any(izn != NVOX);
  const bool axp = __any(ixp != NVOX), axn = __any(ixn != NVOX);
  const bool ayp = __any(iyp != NVOX), ayn = __any(iyn != NVOX);

  bfrag aF[4];   // gathered-neighbor fragments (preissued cross-conv)
  bfrag aS[4];   // self-row fragments (reused by all 3 center taps)

#define LOADF(DST, IDX) {                                                     \
    const char* p = (const char*)fbf + ((size_t)(unsigned)(IDX) << 8) + (lhi << 4); \
    DST[0] = *reinterpret_cast<const bfrag*>(p);                              \
    DST[1] = *reinterpret_cast<const bfrag*>(p + 64);                         \
    DST[2] = *reinterpret_cast<const bfrag*>(p + 128);                        \
    DST[3] = *reinterpret_cast<const bfrag*>(p + 192);                        \
  }

#define TAP(SLOT, AFR, ACCS) {                                                \
    const char* bs = (const char*)Bb + (SLOT) * 16384 + lane * 16;            \
    _Pragma("unroll")                                                         \
    for (int kc = 0; kc < 4; ++kc) {                                          \
      _Pragma("unroll")                                                       \
      for (int ct = 0; ct < 4; ++ct) {                                        \
        const bfrag b = *reinterpret_cast<const bfrag*>(                      \
            bs + (kc * 4 + ct) * 1024);                                       \
        ACCS[ct] = __builtin_amdgcn_mfma_f32_16x16x32_bf16(                   \
            AFR[kc], b, ACCS[ct], 0, 0, 0);                                   \
      } } }

  // One conv BODY; the first-valid off-center gather was preissued into aF.
#define CONVBODY(VP, VN, IN, ACCS)                                            \
  {                                                                           \
    TAP(1, aS, ACCS)                                                          \
    if (VP) {                                                                 \
      TAP(0, aF, ACCS)                                                        \
      if (VN) { LOADF(aF, IN)  TAP(2, aF, ACCS) }                             \
    } else if (VN) {                                                          \
      TAP(2, aF, ACCS)                                                        \
    }                                                                         \
  }

  LOADF(aS, row)                                  // self row (reused 3x)
  if (azp)      LOADF(aF, izp)                    // conv-z preissue: hidden
  else if (azn) LOADF(aF, izn)                    // under the B-fill wait

  __syncthreads();   // conv-z B ready (drains the load-lds queue)

  f4 acc[4], run[4];
#pragma unroll
  for (int ct = 0; ct < 4; ++ct) {
    acc[ct] = f4{0.f, 0.f, 0.f, 0.f};
    run[ct] = f4{0.f, 0.f, 0.f, 0.f};
  }

  // ================= conv-z (W1) =================
  CONVBODY(azp, azn, izn, acc)
  __syncthreads();            // conv-z B readers done
  fillconv(6);                // issue conv-x (W3) fill
  if (axp)      LOADF(aF, ixp)   // conv-x preissue: hidden under fold+drain
  else if (axn) LOADF(aF, ixn)
  // fold: run = sigmoid(bn2(sigmoid(bn0(acc)))); acc = 0
#pragma unroll
  for (int ct = 0; ct < 4; ++ct) {
    const int col = cb * 64 + ct * 16 + l15;
    const float sc0 = bn[0 * CCH + col], sh0 = bn[1 * CCH + col];
    const float sc2 = bn[2 * CCH + col], sh2 = bn[3 * CCH + col];
#pragma unroll
    for (int j = 0; j < 4; ++j) {
      const float u = sigmoidf_(sc0 * acc[ct][j] + sh0);
      run[ct][j] = sigmoidf_(sc2 * u + sh2);
    }
    acc[ct] = f4{0.f, 0.f, 0.f, 0.f};
  }
  __syncthreads();            // conv-x B ready

  // ================= conv-x (W3) =================
  CONVBODY(axp, axn, ixn, acc)
  __syncthreads();            // conv-x B readers done
  fillconv(3);                // issue conv-y (W2) fill
  if (ayp)      LOADF(aF, iyp)   // conv-y preissue
  else if (ayn) LOADF(aF, iyn)
  // fold: run += sigmoid(bn3(acc))
#pragma unroll
  for (int ct = 0; ct < 4; ++ct) {
    const int col = cb * 64 + ct * 16 + l15;
    const float sc3 = bn[4 * CCH + col], sh3 = bn[5 * CCH + col];
#pragma unroll
    for (int j = 0; j < 4; ++j)
      run[ct][j] += sigmoidf_(sc3 * acc[ct][j] + sh3);
  }
  __syncthreads();            // conv-y B ready

  // ================= conv-y (W2), raw into run =================
  CONVBODY(ayp, ayn, iyn, run)

#undef CONVBODY
#undef TAP
#undef LOADF

  // ---- epilogue: multiply by features (bf16, cache-hot), store fp32 ----
#pragma unroll
  for (int ct = 0; ct < 4; ++ct) {
    const int col = cb * 64 + ct * 16 + l15;
#pragma unroll
    for (int j = 0; j < 4; ++j) {
      const int r = wrow + (lhi << 2) + j;
      const size_t o = ((size_t)r << 7) + col;
      out[o] = run[ct][j] * bf2f(fbf[o]);
    }
  }
}

// ---------------------------------------------------------------------------
// Last-resort fallback: exact fp32
// ---------------------------------------------------------------------------
__global__ void recon_naive(const float* __restrict__ feats,
    const float* __restrict__ W1, const float* __restrict__ W2, const float* __restrict__ W3,
    const int* __restrict__ nbrz, const int* __restrict__ nbry, const int* __restrict__ nbrx,
    const float* g0, const float* b0, const float* m0, const float* v0,
    const float* g2, const float* b2, const float* m2, const float* v2,
    const float* g3, const float* b3, const float* m3, const float* v3,
    float* __restrict__ out) {
  __shared__ float rows[3][CCH];
  const int n = blockIdx.x;
  const int d = threadIdx.x;
  float res[3];
#pragma unroll
  for (int conv = 0; conv < 3; ++conv) {
    const int* nbr  = (conv == 0) ? nbrz : ((conv == 1) ? nbry : nbrx);
    const float* W  = (conv == 0) ? W1 : ((conv == 1) ? W2 : W3);
#pragma unroll
    for (int tap = 0; tap < 3; ++tap) {
      const int idx = nbr[n * 3 + tap];
      rows[tap][d] = ((unsigned)idx < (unsigned)NVOX) ? feats[((size_t)idx << 7) + d] : 0.f;
    }
    __syncthreads();
    const float* rflat = &rows[0][0];
    float s = 0.f;
    for (int k = 0; k < 3 * CCH; ++k) s += rflat[k] * W[(size_t)k * CCH + d];
    res[conv] = s;
    __syncthreads();
  }
  const float sc0 = g0[d] * rsqrtf(v0[d] + BN_EPS), sh0 = b0[d] - m0[d] * sc0;
  const float sc2 = g2[d] * rsqrtf(v2[d] + BN_EPS), sh2 = b2[d] - m2[d] * sc2;
  const float sc3 = g3[d] * rsqrtf(v3[d] + BN_EPS), sh3 = b3[d] - m3[d] * sc3;
  float u = 1.f / (1.f + __expf(-(sc0 * res[0] + sh0)));
  u = 1.f / (1.f + __expf(-(sc2 * u + sh2)));
  const float s3v = 1.f / (1.f + __expf(-(sc3 * res[2] + sh3)));
  out[((size_t)n << 7) + d] = (u + res[1] + s3v) * feats[((size_t)n << 7) + d];
}

extern "C" void kernel_launch(void* const* d_in, const int* in_sizes, int n_in,
                              void* d_out, int out_size, void* d_ws, size_t ws_size,
                              hipStream_t stream) {
  const float* feats = (const float*)d_in[0];
  const float* W1 = (const float*)d_in[1];
  const float* W2 = (const float*)d_in[2];
  const float* W3 = (const float*)d_in[3];
  const float* g0 = (const float*)d_in[4];
  const float* b0 = (const float*)d_in[5];
  const float* m0 = (const float*)d_in[6];
  const float* v0 = (const float*)d_in[7];
  const float* g2 = (const float*)d_in[8];
  const float* b2 = (const float*)d_in[9];
  const float* m2 = (const float*)d_in[10];
  const float* v2 = (const float*)d_in[11];
  const float* g3 = (const float*)d_in[12];
  const float* b3 = (const float*)d_in[13];
  const float* m3 = (const float*)d_in[14];
  const float* v3 = (const float*)d_in[15];
  const int* nz = (const int*)d_in[16];
  const int* ny = (const int*)d_in[17];
  const int* nx = (const int*)d_in[18];
  float* out = (float*)d_out;

  const size_t wf_bytes = 288u * 1024u;                              // 294912
  const size_t bn_bytes = 4096u;                                     // 6*128*4 padded
  const size_t fb_bytes = ((size_t)NVOX + 1) * CCH * sizeof(short);  // 67.1 MB
  if (ws_size >= wf_bytes + bn_bytes + fb_bytes) {
    unsigned short* wf  = (unsigned short*)d_ws;
    float*          bnt = (float*)((char*)d_ws + wf_bytes);
    unsigned short* fbf = (unsigned short*)((char*)d_ws + wf_bytes + bn_bytes);
    hipLaunchKernelGGL(prep_wfrag, dim3(288), dim3(64), 0, stream, W1, W2, W3, wf);
    hipLaunchKernelGGL(prep_bn, dim3(1), dim3(CCH), 0, stream,
                       g0, b0, m0, v0, g2, b2, m2, v2, g3, b3, m3, v3, bnt);
    hipLaunchKernelGGL(prep_bf16, dim3((NVOX * CCH) / (256 * 8)), dim3(256), 0, stream,
                       feats, fbf);
    hipLaunchKernelGGL(recon_v20, dim3((NVOX / 128) * 2), dim3(512), 0, stream,
                       fbf, wf, bnt, nz, nx, ny, out);
  } else {
    hipLaunchKernelGGL(recon_naive, dim3(NVOX), dim3(CCH), 0, stream,
                       feats, W1, W2, W3, nz, ny, nx,
                       g0, b0, m0, v0, g2, b2, m2, v2, g3, b3, m3, v3, out);
  }
}